// Round 9
// baseline (75.645 us; speedup 1.0000x reference)
//
#include <hip/hip_runtime.h>
#include <hip/hip_bf16.h>

// Grid_INR2D round 9: round-6 body (best known, 28.8us) + TLP via batch-split.
//  Rounds 7/8 lesson: ILP restructures near the 128-VGPR cap collapse the
//  allocator to 64 VGPR + scratch spill (observed twice). So: attack the
//  latency-bound regime with OCCUPANCY instead (zero extra regs/wave):
//   - gridDim (1024,2): each block does 4 batches -> 2048 blocks, 5+
//     resident blocks/CU possible (prologue duplicated x2, amortized x4).
//   - persistent-reg trim to fit 5 waves/SIMD (launch_bounds(256,5),
//     cap ~102): w1-feat/w3 frags read from LDS each batch (not reg-cached),
//     depth-1 feat prefetch (one raw[8]).
//  Per-batch arithmetic order identical to round 6 -> absmax unchanged.
//  GATES: VGPR ~90-102 (64 = spill collapse -> revert), WRITE_SIZE 6144KB.
// Fragment identity (validated rounds 3-8):
//   A: row=lane&15, k=4*(lane>>4)+(e&3)+16*(e>>2); B: col=lane&15, same k;
//   C/D: col=lane&15, row=4*(lane>>4)+reg  ==> C-frag of layer n is B-frag
//   of layer n+1 per-lane: B[kb].e = bf16(relu(C[2kb+(e>=4)].reg[e&3])).

typedef float f32x4 __attribute__((ext_vector_type(4)));
typedef short s16x8 __attribute__((ext_vector_type(8)));

#define MFMA16(a, b, c) __builtin_amdgcn_mfma_f32_16x16x32_bf16((a), (b), (c), 0, 0, 0)

__device__ __forceinline__ short bfbits(float f) {   // RNE via HW cvt
    return __builtin_bit_cast(short, __float2bfloat16(f));
}

__device__ __forceinline__ s16x8 pack_relu(const f32x4 lo, const f32x4 hi) {
    s16x8 r;
#pragma unroll
    for (int e = 0; e < 4; ++e) {
        r[e]     = bfbits(fmaxf(lo[e], 0.0f));
        r[e + 4] = bfbits(fmaxf(hi[e], 0.0f));
    }
    return r;
}

// LDS frag table: fid 0..11 = w1[mt*3+kb], 12..19 = w2[mt*2+kb], 20..21 = w3[kb]
#define NFRAG 22

__global__ __launch_bounds__(256, 5) void grid_inr_mfma(
    const float* __restrict__ feat,
    const float* __restrict__ g0, const float* __restrict__ g1,
    const float* __restrict__ g2, const float* __restrict__ g3,
    const float* __restrict__ w1, const float* __restrict__ b1,
    const float* __restrict__ w2, const float* __restrict__ b2,
    const float* __restrict__ w3, const float* __restrict__ b3,
    float* __restrict__ out)
{
    __shared__ __align__(16) short lds_w[NFRAG * 64 * 8];

    const int lane  = threadIdx.x & 63;
    const int col   = lane & 15;    // A row / B col / pixel-in-tile
    const int lrow  = lane >> 4;    // k-group
    const int wv    = threadIdx.x >> 6;
    const int p     = blockIdx.x * 64 + wv * 16 + col;   // this lane's pixel
    const int b0    = blockIdx.y * 4;                    // first of 4 batches

    // ---------------- stage weight A-frags into LDS (once per block) -------
    {
        const int cs = lane, c15 = lane & 15, r4 = lane >> 4;
#pragma unroll 1
        for (int fid = threadIdx.x >> 6; fid < NFRAG; fid += 4) {
            const float* src;
            if (fid < 12) {
                const int mt = fid / 3, kb = fid - 3 * mt;
                src = w1 + (16 * mt + c15) * 96 + 32 * kb + 4 * r4;
            } else if (fid < 20) {
                const int f = fid - 12, mt = f >> 1, kb = f & 1;
                src = w2 + (16 * mt + c15) * 64 + 32 * kb + 4 * r4;
            } else {
                const int kb = fid - 20;
                const int row3 = (c15 < 3) ? c15 : 2;   // junk rows unused
                src = w3 + row3 * 64 + 32 * kb + 4 * r4;
            }
            s16x8 frag;
#pragma unroll
            for (int e = 0; e < 8; ++e)
                frag[e] = bfbits(src[(e & 3) + 16 * (e >> 2)]);
            *(s16x8*)&lds_w[(fid * 64 + cs) * 8] = frag;
        }
    }

    // ---------------- biases (f32 regs, per-lane rows; b3 uniform SGPR) -----
    f32x4 b1f[4], b2f[4];
#pragma unroll
    for (int mt = 0; mt < 4; ++mt) {
        b1f[mt] = *(const f32x4*)(b1 + 16 * mt + 4 * lrow);
        b2f[mt] = *(const f32x4*)(b2 + 16 * mt + 4 * lrow);
    }
    const float b3s0 = b3[0], b3s1 = b3[1], b3s2 = b3[2];

    // ---------------- grid-sample -> localB[2] (B-frags, k=local ch) --------
    s16x8 localB[2];
    {
        const float* gs[4] = {g0, g1, g2, g3};
        const int    gn[4] = {32, 64, 128, 256};
        const int px = p & 255;
        const int py = p >> 8;
#pragma unroll
        for (int lv = 0; lv < 4; ++lv) {
            const int G = gn[lv];
            const float ix = (float)((2 * px + 1) * (G - 1)) * (1.0f / 512.0f);
            const float iy = (float)((2 * py + 1) * (G - 1)) * (1.0f / 512.0f);
            int ix0 = (int)ix;
            int iy0 = (int)iy;
            if (ix0 > G - 1) ix0 = G - 1;
            if (iy0 > G - 1) iy0 = G - 1;
            const int ix1 = (ix0 + 1 < G - 1) ? (ix0 + 1) : (G - 1);
            const int iy1 = (iy0 + 1 < G - 1) ? (iy0 + 1) : (G - 1);
            const float wx = ix - (float)ix0;
            const float wy = iy - (float)iy0;
            const float w00 = (1.0f - wy) * (1.0f - wx);
            const float w01 = (1.0f - wy) * wx;
            const float w10 = wy * (1.0f - wx);
            const float w11 = wy * wx;
            const int o00 = iy0 * G + ix0;
            const int o01 = iy0 * G + ix1;
            const int o10 = iy1 * G + ix0;
            const int o11 = iy1 * G + ix1;
            const float* g = gs[lv];
            const int GG = G * G;
#pragma unroll
            for (int j = 0; j < 4; ++j) {
                const float* gc = g + (4 * lrow + j) * GG;
                const float v = gc[o00] * w00 + gc[o01] * w01 +
                                gc[o10] * w10 + gc[o11] * w11;
                localB[lv >> 1][(lv & 1) * 4 + j] = bfbits(v);
            }
        }
    }

    // issue first batch's feat loads before the barrier (independent of LDS)
    float raw[8];
#pragma unroll
    for (int e = 0; e < 8; ++e) {
        const int fc = 4 * lrow + (e & 3) + 16 * (e >> 2);
        raw[e] = feat[(((b0 << 5) | fc) << 16) + p];
    }

    __syncthreads();   // LDS frag table ready

    const short* lw = lds_w + lane * 8;      // per-lane base; fid via offset
#define LDSFRAG(fid) (*(const s16x8*)(lw + (fid) * 64 * 8))

    // c1base[mt] = b1 + W1[:,32:96] . local   (batch-invariant, once)
    f32x4 c1base[4];
#pragma unroll
    for (int mt = 0; mt < 4; ++mt) {
        c1base[mt] = b1f[mt];
        c1base[mt] = MFMA16(LDSFRAG(mt * 3 + 1), localB[0], c1base[mt]);
        c1base[mt] = MFMA16(LDSFRAG(mt * 3 + 2), localB[1], c1base[mt]);
    }
    // localB / b1f dead from here.

    // ---------------- per-batch MLP (4 batches, depth-1 prefetch) -----------
#pragma unroll 1
    for (int bi = 0; bi < 4; ++bi) {
        const int b = b0 + bi;

        // consume this batch's feat, then immediately prefetch next batch
        s16x8 ff;
#pragma unroll
        for (int e = 0; e < 8; ++e) ff[e] = bfbits(raw[e]);
        if (bi < 3) {
#pragma unroll
            for (int e = 0; e < 8; ++e) {
                const int fc = 4 * lrow + (e & 3) + 16 * (e >> 2);
                raw[e] = feat[((((b + 1) << 5) | fc) << 16) + p];
            }
        }

        // layer 1: single MFMA per mtile, seeded from batch-invariant base
        f32x4 c1[4];
#pragma unroll
        for (int mt = 0; mt < 4; ++mt)
            c1[mt] = MFMA16(LDSFRAG(mt * 3), ff, c1base[mt]);

        // relu+repack: C-frag is next layer's B-frag per-lane
        s16x8 h1b0 = pack_relu(c1[0], c1[1]);
        s16x8 h1b1 = pack_relu(c1[2], c1[3]);

        // layer 2 (8 frags streamed from LDS)
        f32x4 c2[4];
#pragma unroll
        for (int mt = 0; mt < 4; ++mt) {
            c2[mt] = b2f[mt];
            c2[mt] = MFMA16(LDSFRAG(12 + mt * 2),     h1b0, c2[mt]);
            c2[mt] = MFMA16(LDSFRAG(12 + mt * 2 + 1), h1b1, c2[mt]);
        }
        s16x8 h2b0 = pack_relu(c2[0], c2[1]);
        s16x8 h2b1 = pack_relu(c2[2], c2[3]);

        // layer 3 (rows 0..2 valid) + store
        f32x4 c3 = {0.f, 0.f, 0.f, 0.f};
        c3 = MFMA16(LDSFRAG(20), h2b0, c3);
        c3 = MFMA16(LDSFRAG(21), h2b1, c3);

        if (lrow == 0) {
            out[((b * 3 + 0) << 16) + p] = c3[0] + b3s0;
            out[((b * 3 + 1) << 16) + p] = c3[1] + b3s1;
            out[((b * 3 + 2) << 16) + p] = c3[2] + b3s2;
        }
    }
#undef LDSFRAG
}

extern "C" void kernel_launch(void* const* d_in, const int* in_sizes, int n_in,
                              void* d_out, int out_size, void* d_ws, size_t ws_size,
                              hipStream_t stream) {
    const float* feat = (const float*)d_in[0];
    const float* g0   = (const float*)d_in[1];
    const float* g1   = (const float*)d_in[2];
    const float* g2   = (const float*)d_in[3];
    const float* g3   = (const float*)d_in[4];
    const float* w1   = (const float*)d_in[5];
    const float* b1   = (const float*)d_in[6];
    const float* w2   = (const float*)d_in[7];
    const float* b2   = (const float*)d_in[8];
    const float* w3   = (const float*)d_in[9];
    const float* b3   = (const float*)d_in[10];

    // x: 65536 px / 64 px-per-block = 1024;  y: 2 batch-slices (4 b each).
    dim3 grid(1024, 2);
    grid_inr_mfma<<<grid, 256, 0, stream>>>(
        feat, g0, g1, g2, g3, w1, b1, w2, b2, w3, b3, (float*)d_out);
}

// Round 10
// 72.111 us; speedup vs baseline: 1.0490x; 1.0490x over previous
//
#include <hip/hip_runtime.h>
#include <hip/hip_bf16.h>

// Grid_INR2D round 10: round-6 body VERBATIM + batch-split across blocks.
//  Round 9 post-mortem: (256,5) cap -> allocator collapse (VGPR 48, 72MB
//  spill). Third collapse event; (256,4) + round-6 body is the only
//  verified-stable codegen point. Round 9 confounded batch-split (good idea)
//  with reg-trim (bad implementation) -> redo batch-split as the ONLY change.
//  Rationale: grid 1024 = exactly 4 resident blocks/CU -> dur == per-block
//  serial time (~60k cy) dominated by latency bubbles, with no spare blocks
//  to fill them. grid (1024,2) x 4-batches: 4 resident + 4 queued per CU.
//  GATES: VGPR 96..128 (64/48 = collapse -> revert), WRITE_SIZE 6144 KB.
// Fragment identity (validated rounds 3-9):
//   A: row=lane&15, k=4*(lane>>4)+(e&3)+16*(e>>2); B: col=lane&15, same k;
//   C/D: col=lane&15, row=4*(lane>>4)+reg  ==> C-frag of layer n is B-frag
//   of layer n+1 per-lane: B[kb].e = bf16(relu(C[2kb+(e>=4)].reg[e&3])).

typedef float f32x4 __attribute__((ext_vector_type(4)));
typedef short s16x8 __attribute__((ext_vector_type(8)));

#define MFMA16(a, b, c) __builtin_amdgcn_mfma_f32_16x16x32_bf16((a), (b), (c), 0, 0, 0)

__device__ __forceinline__ short bfbits(float f) {   // RNE via HW cvt
    return __builtin_bit_cast(short, __float2bfloat16(f));
}

__device__ __forceinline__ s16x8 pack_relu(const f32x4 lo, const f32x4 hi) {
    s16x8 r;
#pragma unroll
    for (int e = 0; e < 4; ++e) {
        r[e]     = bfbits(fmaxf(lo[e], 0.0f));
        r[e + 4] = bfbits(fmaxf(hi[e], 0.0f));
    }
    return r;
}

// LDS frag table: fid 0..11 = w1[mt*3+kb], 12..19 = w2[mt*2+kb], 20..21 = w3[kb]
#define NFRAG 22

__global__ __launch_bounds__(256, 4) void grid_inr_mfma(
    const float* __restrict__ feat,
    const float* __restrict__ g0, const float* __restrict__ g1,
    const float* __restrict__ g2, const float* __restrict__ g3,
    const float* __restrict__ w1, const float* __restrict__ b1,
    const float* __restrict__ w2, const float* __restrict__ b2,
    const float* __restrict__ w3, const float* __restrict__ b3,
    float* __restrict__ out)
{
    __shared__ __align__(16) short lds_w[NFRAG * 64 * 8];

    const int lane  = threadIdx.x & 63;
    const int col   = lane & 15;    // A row / B col / pixel-in-tile
    const int lrow  = lane >> 4;    // k-group
    const int wv    = threadIdx.x >> 6;
    const int p     = blockIdx.x * 64 + wv * 16 + col;   // this lane's pixel
    const int b0    = blockIdx.y * 4;                    // first of 4 batches

    // ---------------- stage weight A-frags into LDS (once per block) -------
    {
        const int cs = lane, c15 = lane & 15, r4 = lane >> 4;
#pragma unroll 1
        for (int fid = threadIdx.x >> 6; fid < NFRAG; fid += 4) {
            const float* src;
            if (fid < 12) {
                const int mt = fid / 3, kb = fid - 3 * mt;
                src = w1 + (16 * mt + c15) * 96 + 32 * kb + 4 * r4;
            } else if (fid < 20) {
                const int f = fid - 12, mt = f >> 1, kb = f & 1;
                src = w2 + (16 * mt + c15) * 64 + 32 * kb + 4 * r4;
            } else {
                const int kb = fid - 20;
                const int row3 = (c15 < 3) ? c15 : 2;   // junk rows unused
                src = w3 + row3 * 64 + 32 * kb + 4 * r4;
            }
            s16x8 frag;
#pragma unroll
            for (int e = 0; e < 8; ++e)
                frag[e] = bfbits(src[(e & 3) + 16 * (e >> 2)]);
            *(s16x8*)&lds_w[(fid * 64 + cs) * 8] = frag;
        }
    }

    // ---------------- biases in regs (f32, per-lane rows) -------------------
    f32x4 b1f[4], b2f[4];
#pragma unroll
    for (int mt = 0; mt < 4; ++mt) {
        b1f[mt] = *(const f32x4*)(b1 + 16 * mt + 4 * lrow);
        b2f[mt] = *(const f32x4*)(b2 + 16 * mt + 4 * lrow);
    }
    const float b3s0 = b3[0], b3s1 = b3[1], b3s2 = b3[2];  // uniform s_loads

    // ---------------- grid-sample -> localB[2] (B-frags, k=local ch) --------
    s16x8 localB[2];
    {
        const float* gs[4] = {g0, g1, g2, g3};
        const int    gn[4] = {32, 64, 128, 256};
        const int px = p & 255;
        const int py = p >> 8;
#pragma unroll
        for (int lv = 0; lv < 4; ++lv) {
            const int G = gn[lv];
            const float ix = (float)((2 * px + 1) * (G - 1)) * (1.0f / 512.0f);
            const float iy = (float)((2 * py + 1) * (G - 1)) * (1.0f / 512.0f);
            int ix0 = (int)ix;
            int iy0 = (int)iy;
            if (ix0 > G - 1) ix0 = G - 1;
            if (iy0 > G - 1) iy0 = G - 1;
            const int ix1 = (ix0 + 1 < G - 1) ? (ix0 + 1) : (G - 1);
            const int iy1 = (iy0 + 1 < G - 1) ? (iy0 + 1) : (G - 1);
            const float wx = ix - (float)ix0;
            const float wy = iy - (float)iy0;
            const float w00 = (1.0f - wy) * (1.0f - wx);
            const float w01 = (1.0f - wy) * wx;
            const float w10 = wy * (1.0f - wx);
            const float w11 = wy * wx;
            const int o00 = iy0 * G + ix0;
            const int o01 = iy0 * G + ix1;
            const int o10 = iy1 * G + ix0;
            const int o11 = iy1 * G + ix1;
            const float* g = gs[lv];
            const int GG = G * G;
#pragma unroll
            for (int j = 0; j < 4; ++j) {
                const float* gc = g + (4 * lrow + j) * GG;
                const float v = gc[o00] * w00 + gc[o01] * w01 +
                                gc[o10] * w10 + gc[o11] * w11;
                localB[lv >> 1][(lv & 1) * 4 + j] = bfbits(v);
            }
        }
    }

    __syncthreads();   // LDS frag table ready

    const short* lw = lds_w + lane * 8;      // per-lane base; fid via offset
#define LDSFRAG(fid) (*(const s16x8*)(lw + (fid) * 64 * 8))

    // ---- register-cache small frag groups; hoist batch-invariant layer-1 ---
    s16x8 w1ff[4], w3f[2];
#pragma unroll
    for (int mt = 0; mt < 4; ++mt) w1ff[mt] = LDSFRAG(mt * 3);
    w3f[0] = LDSFRAG(20);
    w3f[1] = LDSFRAG(21);

    // c1base[mt] = b1 + W1[:,32:96] . local   (batch-invariant, once)
    f32x4 c1base[4];
#pragma unroll
    for (int mt = 0; mt < 4; ++mt) {
        c1base[mt] = b1f[mt];
        c1base[mt] = MFMA16(LDSFRAG(mt * 3 + 1), localB[0], c1base[mt]);
        c1base[mt] = MFMA16(LDSFRAG(mt * 3 + 2), localB[1], c1base[mt]);
    }

    // ---- per-batch MLP body ------------------------------------------------
    auto process = [&](int b, const s16x8 ff) {
        f32x4 c1[4];
#pragma unroll
        for (int mt = 0; mt < 4; ++mt)
            c1[mt] = MFMA16(w1ff[mt], ff, c1base[mt]);

        s16x8 h1b0 = pack_relu(c1[0], c1[1]);
        s16x8 h1b1 = pack_relu(c1[2], c1[3]);

        f32x4 c2[4];
#pragma unroll
        for (int mt = 0; mt < 4; ++mt) {
            c2[mt] = b2f[mt];
            c2[mt] = MFMA16(LDSFRAG(12 + mt * 2),     h1b0, c2[mt]);
            c2[mt] = MFMA16(LDSFRAG(12 + mt * 2 + 1), h1b1, c2[mt]);
        }
        s16x8 h2b0 = pack_relu(c2[0], c2[1]);
        s16x8 h2b1 = pack_relu(c2[2], c2[3]);

        f32x4 c3 = {0.f, 0.f, 0.f, 0.f};
        c3 = MFMA16(w3f[0], h2b0, c3);
        c3 = MFMA16(w3f[1], h2b1, c3);

        if (lrow == 0) {
            out[((b * 3 + 0) << 16) + p] = c3[0] + b3s0;
            out[((b * 3 + 1) << 16) + p] = c3[1] + b3s1;
            out[((b * 3 + 2) << 16) + p] = c3[2] + b3s2;
        }
    };

    // ---- batch loop: 4 batches, 2-deep prefetch via named ping-pong --------
    float rawP[8], rawQ[8];
#pragma unroll
    for (int e = 0; e < 8; ++e) {
        const int fc = 4 * lrow + (e & 3) + 16 * (e >> 2);
        rawP[e] = feat[(((b0 << 5) | fc) << 16) + p];            // batch b0
        rawQ[e] = feat[((((b0 + 1) << 5) | fc) << 16) + p];      // batch b0+1
    }

#pragma unroll 1
    for (int bp = 0; bp < 2; ++bp) {
        const int bA = b0 + 2 * bp;
        // batch A (from rawP); refill rawP with batch bA+2
        s16x8 ff;
#pragma unroll
        for (int e = 0; e < 8; ++e) ff[e] = bfbits(rawP[e]);
        if (bp < 1) {
#pragma unroll
            for (int e = 0; e < 8; ++e) {
                const int fc = 4 * lrow + (e & 3) + 16 * (e >> 2);
                rawP[e] = feat[((((bA + 2) << 5) | fc) << 16) + p];
            }
        }
        process(bA, ff);

        // batch B = bA+1 (from rawQ); refill rawQ with batch bA+3
#pragma unroll
        for (int e = 0; e < 8; ++e) ff[e] = bfbits(rawQ[e]);
        if (bp < 1) {
#pragma unroll
            for (int e = 0; e < 8; ++e) {
                const int fc = 4 * lrow + (e & 3) + 16 * (e >> 2);
                rawQ[e] = feat[((((bA + 3) << 5) | fc) << 16) + p];
            }
        }
        process(bA + 1, ff);
    }
#undef LDSFRAG
}

extern "C" void kernel_launch(void* const* d_in, const int* in_sizes, int n_in,
                              void* d_out, int out_size, void* d_ws, size_t ws_size,
                              hipStream_t stream) {
    const float* feat = (const float*)d_in[0];
    const float* g0   = (const float*)d_in[1];
    const float* g1   = (const float*)d_in[2];
    const float* g2   = (const float*)d_in[3];
    const float* g3   = (const float*)d_in[4];
    const float* w1   = (const float*)d_in[5];
    const float* b1   = (const float*)d_in[6];
    const float* w2   = (const float*)d_in[7];
    const float* b2   = (const float*)d_in[8];
    const float* w3   = (const float*)d_in[9];
    const float* b3   = (const float*)d_in[10];

    // x: 65536 px / 64 px-per-block = 1024;  y: 2 batch-slices (4 b each).
    // 2048 blocks -> 4 resident + 4 queued per CU (VGPR<=128 at (256,4)).
    dim3 grid(1024, 2);
    grid_inr_mfma<<<grid, 256, 0, stream>>>(
        feat, g0, g1, g2, g3, w1, b1, w2, b2, w3, b3, (float*)d_out);
}